// Round 1
// baseline (949.334 us; speedup 1.0000x reference)
//
#include <hip/hip_runtime.h>
#include <stdint.h>

// Problem constants (fixed by setup_inputs)
#define B_SZ 2048          // batch
#define D_SZ 2047          // state dim
#define KD   2048          // D+1 == hash_size == B (required by ref broadcasting)
#define K_SZ 4096          // input_length (rows of A)
#define TABLE_MASK ((1u << 22) - 1)

#define TJ 64              // batch tile
#define TK 64              // k tile
#define BKK 32             // inner-dim step

// C[j,k] = dot(S[j,:], A[k,:]) with S[j,d] = (d<2047 ? states[j,d] : actions[j])
// bit[j,k] = (C[j,k] + b[j]) > 0
// hash[j] += bit * hash_coeffs[k]   (uint32, exact; 2^22 | 2^32 so wrap is safe)
__global__ __launch_bounds__(256)
void opiq_gemm_hash(const float* __restrict__ states,
                    const float* __restrict__ actions,
                    const float* __restrict__ A,
                    const float* __restrict__ bvec,
                    const int* __restrict__ hash_coeffs,
                    unsigned int* __restrict__ hash_acc)
{
    __shared__ float Slds[TJ][BKK + 1];   // +1 pad -> conflict-free column reads
    __shared__ float Alds[TK][BKK + 1];

    const int tid = threadIdx.x;
    const int tx = tid & 15;   // k direction (16 threads)
    const int ty = tid >> 4;   // j direction (16 threads)
    const int j0 = blockIdx.y * TJ;
    const int k0 = blockIdx.x * TK;

    double acc[4][4];
#pragma unroll
    for (int i = 0; i < 4; ++i)
#pragma unroll
        for (int jj = 0; jj < 4; ++jj) acc[i][jj] = 0.0;

    for (int d0 = 0; d0 < KD; d0 += BKK) {
        // Stage S-tile (64x32) and A-tile (64x32): 8 elements each per thread,
        // consecutive tids hit consecutive addresses (coalesced dword loads).
#pragma unroll
        for (int t = 0; t < 8; ++t) {
            int flat = t * 256 + tid;
            int r = flat >> 5;        // 0..63
            int c = flat & 31;        // 0..31
            int d = d0 + c;
            int j = j0 + r;
            Slds[r][c] = (d == D_SZ) ? actions[j] : states[j * D_SZ + d];
            int k = k0 + r;
            Alds[r][c] = A[k * KD + d];
        }
        __syncthreads();

#pragma unroll
        for (int dd = 0; dd < BKK; ++dd) {
            double s[4], a[4];
#pragma unroll
            for (int i = 0; i < 4; ++i) s[i] = (double)Slds[ty * 4 + i][dd];
#pragma unroll
            for (int jj = 0; jj < 4; ++jj) a[jj] = (double)Alds[tx * 4 + jj][dd];
#pragma unroll
            for (int i = 0; i < 4; ++i)
#pragma unroll
                for (int jj = 0; jj < 4; ++jj)
                    acc[i][jj] = fma(s[i], a[jj], acc[i][jj]);
        }
        __syncthreads();
    }

    // Epilogue: bits -> weighted partial hash per batch row
#pragma unroll
    for (int i = 0; i < 4; ++i) {
        const int j = j0 + ty * 4 + i;
        const double bj = (double)bvec[j];
        unsigned int sum = 0;
#pragma unroll
        for (int jj = 0; jj < 4; ++jj) {
            const int k = k0 + tx * 4 + jj;
            const double x = acc[i][jj] + bj;
            if (x > 0.0) sum += (unsigned int)hash_coeffs[k];
        }
        // reduce across tx (lane bits 0..3 within the wave)
        unsigned int v = sum;
        v += (unsigned int)__shfl_xor((int)v, 1);
        v += (unsigned int)__shfl_xor((int)v, 2);
        v += (unsigned int)__shfl_xor((int)v, 4);
        v += (unsigned int)__shfl_xor((int)v, 8);
        if (tx == 0) atomicAdd(&hash_acc[j], v);
    }
}

__global__ void opiq_final(const unsigned int* __restrict__ hash_acc,
                           const int* __restrict__ count_table,
                           float* __restrict__ out)
{
    int j = blockIdx.x * 256 + threadIdx.x;
    if (j < B_SZ) {
        unsigned int idx = hash_acc[j] & TABLE_MASK;
        float c = (float)count_table[idx];
        float t = c + 1.0f;
        out[j] = 1.0f / (t * t);
    }
}

extern "C" void kernel_launch(void* const* d_in, const int* in_sizes, int n_in,
                              void* d_out, int out_size, void* d_ws, size_t ws_size,
                              hipStream_t stream) {
    const float* states       = (const float*)d_in[0];
    const float* actions      = (const float*)d_in[1];
    const float* A            = (const float*)d_in[2];
    const float* bvec         = (const float*)d_in[3];
    const int*   count_table  = (const int*)d_in[4];
    const int*   hash_coeffs  = (const int*)d_in[5];
    float* out = (float*)d_out;

    unsigned int* hash_acc = (unsigned int*)d_ws;
    hipMemsetAsync(hash_acc, 0, B_SZ * sizeof(unsigned int), stream);

    dim3 grid(K_SZ / TK, B_SZ / TJ);   // (64, 32) = 2048 blocks
    opiq_gemm_hash<<<grid, 256, 0, stream>>>(states, actions, A, bvec,
                                             hash_coeffs, hash_acc);
    opiq_final<<<(B_SZ + 255) / 256, 256, 0, stream>>>(hash_acc, count_table, out);
}

// Round 2
// 508.193 us; speedup vs baseline: 1.8681x; 1.8681x over previous
//
#include <hip/hip_runtime.h>
#include <stdint.h>

// Problem constants (fixed by setup_inputs)
#define B_SZ 2048          // batch
#define D_SZ 2047          // state dim
#define KD   2048          // D+1 == hash_size
#define K_SZ 4096          // input_length (rows of A)
#define TABLE_MASK ((1u << 22) - 1)

#define TJ 128             // batch tile
#define TK 128             // k tile
#define BK 16              // inner-dim step
#define LDP (TJ + 4)       // 132-float LDS pitch: rows 16B-aligned, staging writes 2-way max
#define MARGIN 0.01f       // fp32 sign-trust margin (fp32 dot error: rms ~5e-5, bound ~3e-3)

// Main fp32 GEMM + sign + hash. Borderline |x|<=MARGIN dots are deferred to an
// exact fp64 fixup pass, so the final sign decisions are bitwise identical to a
// pure-fp64 kernel.
__global__ __launch_bounds__(256)
void opiq_gemm_hash(const float* __restrict__ states,
                    const float* __restrict__ actions,
                    const float* __restrict__ A,
                    const float* __restrict__ bvec,
                    const int* __restrict__ hash_coeffs,
                    unsigned int* __restrict__ hash_acc,
                    unsigned int* __restrict__ defer_cnt,
                    unsigned int* __restrict__ defer_list,
                    unsigned int defer_cap)
{
    __shared__ float Sl[BK][LDP];   // d-major: Sl[dd][j]
    __shared__ float Al[BK][LDP];   // d-major: Al[dd][k]

    const int tid = threadIdx.x;
    const int tx = tid & 15;        // k direction (16)
    const int ty = tid >> 4;        // j direction (16)
    const int j0 = blockIdx.y * TJ;
    const int k0 = blockIdx.x * TK;

    float acc[8][8];
#pragma unroll
    for (int i = 0; i < 8; ++i)
#pragma unroll
        for (int jj = 0; jj < 8; ++jj) acc[i][jj] = 0.0f;

    for (int d0 = 0; d0 < KD; d0 += BK) {
        // ---- stage S tile (16 d x 128 j), dword loads (states rows are odd-strided)
        // flat = t*256+tid: d = flat&15 (fast-varying -> coalesced), j = flat>>4
        // LDS write bank = (4d + j) % 32 -> exactly 2-way (free)
#pragma unroll
        for (int t = 0; t < 8; ++t) {
            int flat = t * 256 + tid;
            int d = flat & 15;
            int j = flat >> 4;
            int gd = d0 + d;
            Sl[d][j] = (gd == D_SZ) ? actions[j0 + j]
                                    : states[(j0 + j) * D_SZ + gd];
        }
        // ---- stage A tile (16 d x 128 k) via aligned float4 along d
        // flat4 = t*256+tid: dq = flat4&3, k = flat4>>2
#pragma unroll
        for (int t = 0; t < 2; ++t) {
            int flat4 = t * 256 + tid;
            int dq = flat4 & 3;
            int k = flat4 >> 2;
            const float4 v = *reinterpret_cast<const float4*>(
                &A[(size_t)(k0 + k) * KD + d0 + dq * 4]);
            Al[dq * 4 + 0][k] = v.x;
            Al[dq * 4 + 1][k] = v.y;
            Al[dq * 4 + 2][k] = v.z;
            Al[dq * 4 + 3][k] = v.w;
        }
        __syncthreads();

#pragma unroll 4
        for (int dd = 0; dd < BK; ++dd) {
            const float4 s0 = *reinterpret_cast<const float4*>(&Sl[dd][ty * 8]);
            const float4 s1 = *reinterpret_cast<const float4*>(&Sl[dd][ty * 8 + 4]);
            const float4 a0 = *reinterpret_cast<const float4*>(&Al[dd][tx * 8]);
            const float4 a1 = *reinterpret_cast<const float4*>(&Al[dd][tx * 8 + 4]);
            const float s[8] = {s0.x, s0.y, s0.z, s0.w, s1.x, s1.y, s1.z, s1.w};
            const float a[8] = {a0.x, a0.y, a0.z, a0.w, a1.x, a1.y, a1.z, a1.w};
#pragma unroll
            for (int i = 0; i < 8; ++i)
#pragma unroll
                for (int jj = 0; jj < 8; ++jj)
                    acc[i][jj] = fmaf(s[i], a[jj], acc[i][jj]);
        }
        __syncthreads();
    }

    // ---- epilogue: sign -> weighted hash partials; borderline -> defer list
#pragma unroll
    for (int i = 0; i < 8; ++i) {
        const int j = j0 + ty * 8 + i;
        const float bj = bvec[j];
        unsigned int sum = 0;
#pragma unroll
        for (int jj = 0; jj < 8; ++jj) {
            const int k = k0 + tx * 8 + jj;
            const float x = acc[i][jj] + bj;
            if (__builtin_fabsf(x) <= MARGIN) {
                unsigned int slot = atomicAdd(defer_cnt, 1u);
                if (slot < defer_cap)
                    defer_list[slot] = ((unsigned int)j << 12) | (unsigned int)k;
            } else if (x > 0.0f) {
                sum += (unsigned int)hash_coeffs[k];
            }
        }
        // reduce across tx (lane bits 0..3)
        sum += (unsigned int)__shfl_xor((int)sum, 1);
        sum += (unsigned int)__shfl_xor((int)sum, 2);
        sum += (unsigned int)__shfl_xor((int)sum, 4);
        sum += (unsigned int)__shfl_xor((int)sum, 8);
        if (tx == 0) atomicAdd(&hash_acc[j], sum);
    }
}

// Exact fp64 recompute of deferred dots; one wave per deferred (j,k) pair.
__global__ __launch_bounds__(256)
void opiq_fixup(const float* __restrict__ states,
                const float* __restrict__ actions,
                const float* __restrict__ A,
                const float* __restrict__ bvec,
                const int* __restrict__ hash_coeffs,
                unsigned int* __restrict__ hash_acc,
                const unsigned int* __restrict__ defer_cnt,
                const unsigned int* __restrict__ defer_list,
                unsigned int defer_cap)
{
    const int gtid = blockIdx.x * 256 + threadIdx.x;
    const int wave = gtid >> 6;
    const int lane = gtid & 63;
    const int n_waves = gridDim.x * 4;

    unsigned int n = *defer_cnt;
    if (n > defer_cap) n = defer_cap;

    for (unsigned int e = wave; e < n; e += n_waves) {
        const unsigned int ent = defer_list[e];
        const int j = (int)(ent >> 12);
        const int k = (int)(ent & 4095);
        double part = 0.0;
        const int dbase = lane * 32;
#pragma unroll 8
        for (int t = 0; t < 32; ++t) {
            const int d = dbase + t;
            const float sv = (d == D_SZ) ? actions[j]
                                         : states[(size_t)j * D_SZ + d];
            part = fma((double)sv, (double)A[(size_t)k * KD + d], part);
        }
#pragma unroll
        for (int m = 1; m < 64; m <<= 1)
            part += __shfl_xor(part, m);
        const double x = part + (double)bvec[j];
        if (lane == 0 && x > 0.0)
            atomicAdd(&hash_acc[j], (unsigned int)hash_coeffs[k]);
    }
}

__global__ void opiq_final(const unsigned int* __restrict__ hash_acc,
                           const int* __restrict__ count_table,
                           float* __restrict__ out)
{
    int j = blockIdx.x * 256 + threadIdx.x;
    if (j < B_SZ) {
        unsigned int idx = hash_acc[j] & TABLE_MASK;
        float c = (float)count_table[idx];
        float t = c + 1.0f;
        out[j] = 1.0f / (t * t);
    }
}

extern "C" void kernel_launch(void* const* d_in, const int* in_sizes, int n_in,
                              void* d_out, int out_size, void* d_ws, size_t ws_size,
                              hipStream_t stream) {
    const float* states      = (const float*)d_in[0];
    const float* actions     = (const float*)d_in[1];
    const float* A           = (const float*)d_in[2];
    const float* bvec        = (const float*)d_in[3];
    const int*   count_table = (const int*)d_in[4];
    const int*   hash_coeffs = (const int*)d_in[5];
    float* out = (float*)d_out;

    // workspace layout: [0, 8K) hash_acc; [8K, 8K+4) defer counter; rest: defer list
    unsigned int* hash_acc   = (unsigned int*)d_ws;
    unsigned int* defer_cnt  = hash_acc + B_SZ;
    unsigned int* defer_list = hash_acc + B_SZ + 1;
    unsigned int  defer_cap  = 0;
    if (ws_size > (B_SZ + 1) * sizeof(unsigned int))
        defer_cap = (unsigned int)((ws_size - (B_SZ + 1) * sizeof(unsigned int))
                                   / sizeof(unsigned int));
    if (defer_cap > (1u << 20)) defer_cap = 1u << 20;   // plenty; expected ~1.5K

    hipMemsetAsync(d_ws, 0, (B_SZ + 1) * sizeof(unsigned int), stream);

    dim3 grid(K_SZ / TK, B_SZ / TJ);   // (32, 16) = 512 blocks
    opiq_gemm_hash<<<grid, 256, 0, stream>>>(states, actions, A, bvec,
                                             hash_coeffs, hash_acc,
                                             defer_cnt, defer_list, defer_cap);
    opiq_fixup<<<128, 256, 0, stream>>>(states, actions, A, bvec, hash_coeffs,
                                        hash_acc, defer_cnt, defer_list, defer_cap);
    opiq_final<<<(B_SZ + 255) / 256, 256, 0, stream>>>(hash_acc, count_table, out);
}

// Round 3
// 235.409 us; speedup vs baseline: 4.0327x; 2.1588x over previous
//
#include <hip/hip_runtime.h>
#include <stdint.h>

// Problem constants (fixed by setup_inputs)
#define B_SZ 2048          // batch
#define D_SZ 2047          // state dim
#define KD   2048          // D+1 == hash_size
#define K_SZ 4096          // input_length (rows of A)
#define TABLE_MASK ((1u << 22) - 1)

#define TJ 128             // batch tile
#define TK 128             // k tile
#define BK 32              // inner-dim step (== MFMA K)
#define MARGIN 0.03f       // 3-pass bf16-split worst-case error ~1.3e-2; 2.3x headroom

typedef __attribute__((ext_vector_type(8))) short bf16x8;
typedef __attribute__((ext_vector_type(4))) float f32x4;

__device__ __forceinline__ unsigned short f2bf_rn(float x) {
    unsigned int u = __builtin_bit_cast(unsigned int, x);
    unsigned int lsb = (u >> 16) & 1u;
    u += 0x7fffu + lsb;                 // round-to-nearest-even
    return (unsigned short)(u >> 16);
}
__device__ __forceinline__ float bf2f(unsigned short h) {
    unsigned int u = ((unsigned int)h) << 16;
    return __builtin_bit_cast(float, u);
}

// C[j,k] = dot(S[j,:2048], A[k,:2048]),  S[j,d] = (d<2047 ? states[j,d] : actions[j])
// 3-pass bf16 split MFMA; |C+b[j]| <= MARGIN deferred to exact fp64 fixup.
__global__ __launch_bounds__(256)
void opiq_gemm_hash(const float* __restrict__ states,
                    const float* __restrict__ actions,
                    const float* __restrict__ A,
                    const float* __restrict__ bvec,
                    const int* __restrict__ hash_coeffs,
                    unsigned int* __restrict__ hash_acc,
                    unsigned int* __restrict__ defer_cnt,
                    unsigned int* __restrict__ defer_list,
                    unsigned int defer_cap)
{
    __shared__ unsigned short Shi[TJ][BK];   // [j][d] bf16 hi, 64B rows
    __shared__ unsigned short Slo[TJ][BK];
    __shared__ unsigned short Ahi[TK][BK];   // [k][d]
    __shared__ unsigned short Alo[TK][BK];

    const int tid  = threadIdx.x;
    const int lane = tid & 63;
    const int wid  = tid >> 6;        // 4 waves, 2x2
    const int wj   = wid >> 1;        // j half (0..1)
    const int wk   = wid & 1;         // k half (0..1)
    const int j0 = blockIdx.y * TJ;
    const int k0 = blockIdx.x * TK;

    f32x4 acc[4][4];                  // [m][n], wave tile 64x64
#pragma unroll
    for (int m = 0; m < 4; ++m)
#pragma unroll
        for (int n = 0; n < 4; ++n) acc[m][n] = (f32x4){0.f, 0.f, 0.f, 0.f};

    const int srow = tid >> 3;        // 0..31 (staging row within 32-row slab)
    const int sdq  = tid & 7;         // 0..7  (float4 column within BK=32)

    for (int d0 = 0; d0 < KD; d0 += BK) {
        // ---- stage S tile (128 j x 32 d) with on-the-fly hi/lo split.
        // states rows have odd stride 2047 -> scalar dword loads (coalesced in d).
#pragma unroll
        for (int p = 0; p < 4; ++p) {
            const int row = p * 32 + srow;
            const int j = j0 + row;
            float v[4];
#pragma unroll
            for (int e = 0; e < 4; ++e) {
                const int gd = d0 + sdq * 4 + e;
                v[e] = (gd == D_SZ) ? actions[j]
                                    : states[(size_t)j * D_SZ + gd];
            }
            ushort4 h, l;
            h.x = f2bf_rn(v[0]); l.x = f2bf_rn(v[0] - bf2f(h.x));
            h.y = f2bf_rn(v[1]); l.y = f2bf_rn(v[1] - bf2f(h.y));
            h.z = f2bf_rn(v[2]); l.z = f2bf_rn(v[2] - bf2f(h.z));
            h.w = f2bf_rn(v[3]); l.w = f2bf_rn(v[3] - bf2f(h.w));
            *reinterpret_cast<ushort4*>(&Shi[row][sdq * 4]) = h;
            *reinterpret_cast<ushort4*>(&Slo[row][sdq * 4]) = l;
        }
        // ---- stage A tile (128 k x 32 d), aligned float4 loads
#pragma unroll
        for (int p = 0; p < 4; ++p) {
            const int row = p * 32 + srow;
            const float4 v = *reinterpret_cast<const float4*>(
                &A[(size_t)(k0 + row) * KD + d0 + sdq * 4]);
            ushort4 h, l;
            h.x = f2bf_rn(v.x); l.x = f2bf_rn(v.x - bf2f(h.x));
            h.y = f2bf_rn(v.y); l.y = f2bf_rn(v.y - bf2f(h.y));
            h.z = f2bf_rn(v.z); l.z = f2bf_rn(v.z - bf2f(h.z));
            h.w = f2bf_rn(v.w); l.w = f2bf_rn(v.w - bf2f(h.w));
            *reinterpret_cast<ushort4*>(&Ahi[row][sdq * 4]) = h;
            *reinterpret_cast<ushort4*>(&Alo[row][sdq * 4]) = l;
        }
        __syncthreads();

        // ---- MFMA: fragment rows = (lane&15), k = (lane>>4)*8 + e  (16B contig)
        const int frow = lane & 15;
        const int fcol8 = (lane >> 4) * 8;
        bf16x8 sh[4], sl[4];
#pragma unroll
        for (int m = 0; m < 4; ++m) {
            sh[m] = *reinterpret_cast<const bf16x8*>(&Shi[wj * 64 + m * 16 + frow][fcol8]);
            sl[m] = *reinterpret_cast<const bf16x8*>(&Slo[wj * 64 + m * 16 + frow][fcol8]);
        }
#pragma unroll
        for (int n = 0; n < 4; ++n) {
            const bf16x8 ah = *reinterpret_cast<const bf16x8*>(&Ahi[wk * 64 + n * 16 + frow][fcol8]);
            const bf16x8 al = *reinterpret_cast<const bf16x8*>(&Alo[wk * 64 + n * 16 + frow][fcol8]);
#pragma unroll
            for (int m = 0; m < 4; ++m) {
                acc[m][n] = __builtin_amdgcn_mfma_f32_16x16x32_bf16(sh[m], ah, acc[m][n], 0, 0, 0);
                acc[m][n] = __builtin_amdgcn_mfma_f32_16x16x32_bf16(sh[m], al, acc[m][n], 0, 0, 0);
                acc[m][n] = __builtin_amdgcn_mfma_f32_16x16x32_bf16(sl[m], ah, acc[m][n], 0, 0, 0);
            }
        }
        __syncthreads();
    }

    // ---- epilogue: C/D layout col=lane&15, row=(lane>>4)*4+reg  [m89-verified]
#pragma unroll
    for (int m = 0; m < 4; ++m) {
#pragma unroll
        for (int r = 0; r < 4; ++r) {
            const int j = j0 + wj * 64 + m * 16 + (lane >> 4) * 4 + r;
            const float bj = bvec[j];
            unsigned int sum = 0;
#pragma unroll
            for (int n = 0; n < 4; ++n) {
                const int k = k0 + wk * 64 + n * 16 + (lane & 15);
                const float x = acc[m][n][r] + bj;
                if (__builtin_fabsf(x) <= MARGIN) {
                    unsigned int slot = atomicAdd(defer_cnt, 1u);
                    if (slot < defer_cap)
                        defer_list[slot] = ((unsigned int)j << 12) | (unsigned int)k;
                } else if (x > 0.0f) {
                    sum += (unsigned int)hash_coeffs[k];
                }
            }
            sum += (unsigned int)__shfl_xor((int)sum, 1);
            sum += (unsigned int)__shfl_xor((int)sum, 2);
            sum += (unsigned int)__shfl_xor((int)sum, 4);
            sum += (unsigned int)__shfl_xor((int)sum, 8);
            if ((lane & 15) == 0) atomicAdd(&hash_acc[j], sum);
        }
    }
}

// Exact fp64 recompute of deferred dots; one wave per deferred (j,k) pair.
__global__ __launch_bounds__(256)
void opiq_fixup(const float* __restrict__ states,
                const float* __restrict__ actions,
                const float* __restrict__ A,
                const float* __restrict__ bvec,
                const int* __restrict__ hash_coeffs,
                unsigned int* __restrict__ hash_acc,
                const unsigned int* __restrict__ defer_cnt,
                const unsigned int* __restrict__ defer_list,
                unsigned int defer_cap)
{
    const int gtid = blockIdx.x * 256 + threadIdx.x;
    const int wave = gtid >> 6;
    const int lane = gtid & 63;
    const int n_waves = gridDim.x * 4;

    unsigned int n = *defer_cnt;
    if (n > defer_cap) n = defer_cap;

    for (unsigned int e = wave; e < n; e += n_waves) {
        const unsigned int ent = defer_list[e];
        const int j = (int)(ent >> 12);
        const int k = (int)(ent & 4095);
        double part = 0.0;
        const int dbase = lane * 32;
#pragma unroll 8
        for (int t = 0; t < 32; ++t) {
            const int d = dbase + t;
            const float sv = (d == D_SZ) ? actions[j]
                                         : states[(size_t)j * D_SZ + d];
            part = fma((double)sv, (double)A[(size_t)k * KD + d], part);
        }
#pragma unroll
        for (int m = 1; m < 64; m <<= 1)
            part += __shfl_xor(part, m);
        const double x = part + (double)bvec[j];
        if (lane == 0 && x > 0.0)
            atomicAdd(&hash_acc[j], (unsigned int)hash_coeffs[k]);
    }
}

__global__ void opiq_final(const unsigned int* __restrict__ hash_acc,
                           const int* __restrict__ count_table,
                           float* __restrict__ out)
{
    int j = blockIdx.x * 256 + threadIdx.x;
    if (j < B_SZ) {
        unsigned int idx = hash_acc[j] & TABLE_MASK;
        float c = (float)count_table[idx];
        float t = c + 1.0f;
        out[j] = 1.0f / (t * t);
    }
}

extern "C" void kernel_launch(void* const* d_in, const int* in_sizes, int n_in,
                              void* d_out, int out_size, void* d_ws, size_t ws_size,
                              hipStream_t stream) {
    const float* states      = (const float*)d_in[0];
    const float* actions     = (const float*)d_in[1];
    const float* A           = (const float*)d_in[2];
    const float* bvec        = (const float*)d_in[3];
    const int*   count_table = (const int*)d_in[4];
    const int*   hash_coeffs = (const int*)d_in[5];
    float* out = (float*)d_out;

    // workspace: [0, 8K) hash_acc; [8K, 8K+4) defer counter; rest: defer list
    unsigned int* hash_acc   = (unsigned int*)d_ws;
    unsigned int* defer_cnt  = hash_acc + B_SZ;
    unsigned int* defer_list = hash_acc + B_SZ + 1;
    unsigned int  defer_cap  = 0;
    if (ws_size > (B_SZ + 1) * sizeof(unsigned int))
        defer_cap = (unsigned int)((ws_size - (B_SZ + 1) * sizeof(unsigned int))
                                   / sizeof(unsigned int));
    if (defer_cap > (1u << 20)) defer_cap = 1u << 20;   // expected ~4.5K entries

    hipMemsetAsync(d_ws, 0, (B_SZ + 1) * sizeof(unsigned int), stream);

    dim3 grid(K_SZ / TK, B_SZ / TJ);   // (32, 16) = 512 blocks
    opiq_gemm_hash<<<grid, 256, 0, stream>>>(states, actions, A, bvec,
                                             hash_coeffs, hash_acc,
                                             defer_cnt, defer_list, defer_cap);
    opiq_fixup<<<128, 256, 0, stream>>>(states, actions, A, bvec, hash_coeffs,
                                        hash_acc, defer_cnt, defer_list, defer_cap);
    opiq_final<<<(B_SZ + 255) / 256, 256, 0, stream>>>(hash_acc, count_table, out);
}

// Round 4
// 209.862 us; speedup vs baseline: 4.5236x; 1.1217x over previous
//
#include <hip/hip_runtime.h>
#include <stdint.h>

// Problem constants (fixed by setup_inputs)
#define B_SZ 2048          // batch
#define D_SZ 2047          // state dim
#define KD   2048          // D+1 == hash_size
#define K_SZ 4096          // input_length (rows of A)
#define TABLE_MASK ((1u << 22) - 1)

#define TJ 128             // batch tile
#define TK 128             // k tile
#define BK 32              // inner-dim step (== MFMA K)
#define MARGIN 0.03f       // 3-pass bf16-split worst-case error ~1.3e-2; 2.3x headroom

typedef __attribute__((ext_vector_type(8))) short bf16x8;
typedef __attribute__((ext_vector_type(4))) float f32x4;
typedef unsigned short ushort_t;

__device__ __forceinline__ unsigned short f2bf_rn(float x) {
    unsigned int u = __builtin_bit_cast(unsigned int, x);
    unsigned int lsb = (u >> 16) & 1u;
    u += 0x7fffu + lsb;                 // round-to-nearest-even
    return (unsigned short)(u >> 16);
}
__device__ __forceinline__ float bf2f(unsigned short h) {
    unsigned int u = ((unsigned int)h) << 16;
    return __builtin_bit_cast(float, u);
}

__device__ __forceinline__ void gl_lds16(const void* g, void* l) {
    __builtin_amdgcn_global_load_lds(
        (const __attribute__((address_space(1))) unsigned int*)g,
        (__attribute__((address_space(3))) unsigned int*)l, 16, 0, 0);
}

// ---------------------------------------------------------------------------
// Pass 0: split f32 -> (bf16 hi, bf16 lo) planes, with the 16B-chunk XOR
// swizzle PRE-BAKED into the global layout (key = (row>>1)&3 on d bits 3..4).
// GEMM then stages linearly via global_load_lds and reads with the same XOR.
// ---------------------------------------------------------------------------
__global__ __launch_bounds__(256)
void opiq_split(const float* __restrict__ states,
                const float* __restrict__ actions,
                const float* __restrict__ A,
                ushort_t* __restrict__ Shi, ushort_t* __restrict__ Slo,
                ushort_t* __restrict__ Ahi, ushort_t* __restrict__ Alo)
{
    const long long NS = (long long)B_SZ * KD;      // 4.19M
    const long long NA = (long long)K_SZ * KD;      // 8.39M
    const long long stride = (long long)gridDim.x * 256;
    for (long long i = (long long)blockIdx.x * 256 + threadIdx.x;
         i < NS + NA; i += stride) {
        float v; int r, d; ushort_t *hi, *lo;
        if (i < NS) {
            r = (int)(i >> 11); d = (int)(i & 2047);
            v = (d == D_SZ) ? actions[r] : states[(size_t)r * D_SZ + d];
            hi = Shi; lo = Slo;
        } else {
            long long ii = i - NS;
            r = (int)(ii >> 11); d = (int)(ii & 2047);
            v = A[(size_t)r * KD + d];
            hi = Ahi; lo = Alo;
        }
        const int key = (r >> 1) & 3;
        const int dd = (d & ~24) | ((((d >> 3) & 3) ^ key) << 3);
        const ushort_t h = f2bf_rn(v);
        const float res = v - bf2f(h);          // exact in f32
        const ushort_t l2 = f2bf_rn(res);
        hi[(size_t)r * KD + dd] = h;
        lo[(size_t)r * KD + dd] = l2;
    }
}

// ---------------------------------------------------------------------------
// Main GEMM: 128x128 tile, BK=32, 4 waves (2x2), 3-pass bf16-split MFMA.
// 2-phase pipeline: STAGE(next) issued before ds_read+MFMA(cur); one barrier
// per K-step. LDS double-buffered (64 KB). Borderline dots -> fp64 fixup.
// ---------------------------------------------------------------------------
__global__ __launch_bounds__(256)
void opiq_gemm_mfma(const ushort_t* __restrict__ Shi, const ushort_t* __restrict__ Slo,
                    const ushort_t* __restrict__ Ahi, const ushort_t* __restrict__ Alo,
                    const float* __restrict__ bvec,
                    const int* __restrict__ hash_coeffs,
                    unsigned int* __restrict__ hash_acc,
                    unsigned int* __restrict__ defer_cnt,
                    unsigned int* __restrict__ defer_list,
                    unsigned int defer_cap)
{
    // [buf][plane: Shi,Slo,Ahi,Alo][128 rows x 32 bf16]
    __shared__ __align__(16) ushort_t lds[2][4][TJ * BK];

    const int tid  = threadIdx.x;
    const int lane = tid & 63;
    const int w    = tid >> 6;       // wave 0..3
    const int wj   = w >> 1;         // j half
    const int wk   = w & 1;          // k half

    // XCD-aware block swizzle (512 % 8 == 0 -> simple form is bijective)
    const int bid = blockIdx.x;
    const int swz = (bid & 7) * 64 + (bid >> 3);
    const int bx = swz & 31;         // k-tile (32)
    const int by = swz >> 5;         // j-tile (16)
    const int j0 = by * TJ;
    const int k0 = bx * TK;

    const ushort_t* gp[4] = { Shi + (size_t)j0 * KD, Slo + (size_t)j0 * KD,
                              Ahi + (size_t)k0 * KD, Alo + (size_t)k0 * KD };
    // staging chunks: each thread owns 2 of 512 16B-chunks per plane-tile,
    // wave-contiguous so global_load_lds dest = wave base + lane*16.
    const int c1 = w * 64 + lane;
    const int c2 = c1 + 256;

    f32x4 acc[4][4];
#pragma unroll
    for (int m = 0; m < 4; ++m)
#pragma unroll
        for (int n = 0; n < 4; ++n) acc[m][n] = (f32x4){0.f, 0.f, 0.f, 0.f};

    const int frow = lane & 15;
    const int key  = (frow >> 1) & 3;
    const int col  = ((lane >> 4) ^ key) * 8;   // swizzled 16B-chunk (in ushorts)

#define STAGE(buf, t)                                                          \
    do {                                                                       \
        const int d0_ = (t) * BK;                                              \
        _Pragma("unroll")                                                      \
        for (int p_ = 0; p_ < 4; ++p_) {                                       \
            {                                                                  \
                const int row_ = c1 >> 2, cc_ = c1 & 3;                        \
                gl_lds16(gp[p_] + (size_t)row_ * KD + d0_ + cc_ * 8,           \
                         &lds[buf][p_][c1 * 8]);                               \
            }                                                                  \
            {                                                                  \
                const int row_ = c2 >> 2, cc_ = c2 & 3;                        \
                gl_lds16(gp[p_] + (size_t)row_ * KD + d0_ + cc_ * 8,           \
                         &lds[buf][p_][c2 * 8]);                               \
            }                                                                  \
        }                                                                      \
    } while (0)

    STAGE(0, 0);
    __syncthreads();

    for (int t = 0; t < KD / BK; ++t) {
        const int cur = t & 1;
        if (t < KD / BK - 1) STAGE(cur ^ 1, t + 1);

        bf16x8 sh[4], sl[4];
#pragma unroll
        for (int m = 0; m < 4; ++m) {
            const int row = wj * 64 + m * 16 + frow;
            sh[m] = *reinterpret_cast<const bf16x8*>(&lds[cur][0][row * BK + col]);
            sl[m] = *reinterpret_cast<const bf16x8*>(&lds[cur][1][row * BK + col]);
        }
#pragma unroll
        for (int n = 0; n < 4; ++n) {
            const int row = wk * 64 + n * 16 + frow;
            const bf16x8 ah = *reinterpret_cast<const bf16x8*>(&lds[cur][2][row * BK + col]);
            const bf16x8 al = *reinterpret_cast<const bf16x8*>(&lds[cur][3][row * BK + col]);
#pragma unroll
            for (int m = 0; m < 4; ++m) {
                acc[m][n] = __builtin_amdgcn_mfma_f32_16x16x32_bf16(sh[m], ah, acc[m][n], 0, 0, 0);
                acc[m][n] = __builtin_amdgcn_mfma_f32_16x16x32_bf16(sh[m], al, acc[m][n], 0, 0, 0);
                acc[m][n] = __builtin_amdgcn_mfma_f32_16x16x32_bf16(sl[m], ah, acc[m][n], 0, 0, 0);
            }
        }
        __syncthreads();
    }
#undef STAGE

    // ---- epilogue: C/D layout col=lane&15, row=(lane>>4)*4+reg
#pragma unroll
    for (int m = 0; m < 4; ++m) {
#pragma unroll
        for (int r = 0; r < 4; ++r) {
            const int j = j0 + wj * 64 + m * 16 + (lane >> 4) * 4 + r;
            const float bj = bvec[j];
            unsigned int sum = 0;
#pragma unroll
            for (int n = 0; n < 4; ++n) {
                const int k = k0 + wk * 64 + n * 16 + (lane & 15);
                const float x = acc[m][n][r] + bj;
                if (__builtin_fabsf(x) <= MARGIN) {
                    unsigned int slot = atomicAdd(defer_cnt, 1u);
                    if (slot < defer_cap)
                        defer_list[slot] = ((unsigned int)j << 12) | (unsigned int)k;
                } else if (x > 0.0f) {
                    sum += (unsigned int)hash_coeffs[k];
                }
            }
            sum += (unsigned int)__shfl_xor((int)sum, 1);
            sum += (unsigned int)__shfl_xor((int)sum, 2);
            sum += (unsigned int)__shfl_xor((int)sum, 4);
            sum += (unsigned int)__shfl_xor((int)sum, 8);
            if ((lane & 15) == 0) atomicAdd(&hash_acc[j], sum);
        }
    }
}

// ---------------------------------------------------------------------------
// Fallback (R2 kernel, in-loop split) if ws_size can't hold the planes.
// ---------------------------------------------------------------------------
__global__ __launch_bounds__(256)
void opiq_gemm_hash(const float* __restrict__ states,
                    const float* __restrict__ actions,
                    const float* __restrict__ A,
                    const float* __restrict__ bvec,
                    const int* __restrict__ hash_coeffs,
                    unsigned int* __restrict__ hash_acc,
                    unsigned int* __restrict__ defer_cnt,
                    unsigned int* __restrict__ defer_list,
                    unsigned int defer_cap)
{
    __shared__ ushort_t Shi[TJ][BK];
    __shared__ ushort_t Slo[TJ][BK];
    __shared__ ushort_t Ahi[TK][BK];
    __shared__ ushort_t Alo[TK][BK];

    const int tid  = threadIdx.x;
    const int lane = tid & 63;
    const int wid  = tid >> 6;
    const int wj   = wid >> 1;
    const int wk   = wid & 1;
    const int j0 = blockIdx.y * TJ;
    const int k0 = blockIdx.x * TK;

    f32x4 acc[4][4];
#pragma unroll
    for (int m = 0; m < 4; ++m)
#pragma unroll
        for (int n = 0; n < 4; ++n) acc[m][n] = (f32x4){0.f, 0.f, 0.f, 0.f};

    const int srow = tid >> 3;
    const int sdq  = tid & 7;

    for (int d0 = 0; d0 < KD; d0 += BK) {
#pragma unroll
        for (int p = 0; p < 4; ++p) {
            const int row = p * 32 + srow;
            const int j = j0 + row;
            float v[4];
#pragma unroll
            for (int e = 0; e < 4; ++e) {
                const int gd = d0 + sdq * 4 + e;
                v[e] = (gd == D_SZ) ? actions[j] : states[(size_t)j * D_SZ + gd];
            }
            ushort4 h, l;
            h.x = f2bf_rn(v[0]); l.x = f2bf_rn(v[0] - bf2f(h.x));
            h.y = f2bf_rn(v[1]); l.y = f2bf_rn(v[1] - bf2f(h.y));
            h.z = f2bf_rn(v[2]); l.z = f2bf_rn(v[2] - bf2f(h.z));
            h.w = f2bf_rn(v[3]); l.w = f2bf_rn(v[3] - bf2f(h.w));
            *reinterpret_cast<ushort4*>(&Shi[row][sdq * 4]) = h;
            *reinterpret_cast<ushort4*>(&Slo[row][sdq * 4]) = l;
        }
#pragma unroll
        for (int p = 0; p < 4; ++p) {
            const int row = p * 32 + srow;
            const float4 v = *reinterpret_cast<const float4*>(
                &A[(size_t)(k0 + row) * KD + d0 + sdq * 4]);
            ushort4 h, l;
            h.x = f2bf_rn(v.x); l.x = f2bf_rn(v.x - bf2f(h.x));
            h.y = f2bf_rn(v.y); l.y = f2bf_rn(v.y - bf2f(h.y));
            h.z = f2bf_rn(v.z); l.z = f2bf_rn(v.z - bf2f(h.z));
            h.w = f2bf_rn(v.w); l.w = f2bf_rn(v.w - bf2f(h.w));
            *reinterpret_cast<ushort4*>(&Ahi[row][sdq * 4]) = h;
            *reinterpret_cast<ushort4*>(&Alo[row][sdq * 4]) = l;
        }
        __syncthreads();

        const int frow = lane & 15;
        const int fcol8 = (lane >> 4) * 8;
        bf16x8 sh[4], sl[4];
#pragma unroll
        for (int m = 0; m < 4; ++m) {
            sh[m] = *reinterpret_cast<const bf16x8*>(&Shi[wj * 64 + m * 16 + frow][fcol8]);
            sl[m] = *reinterpret_cast<const bf16x8*>(&Slo[wj * 64 + m * 16 + frow][fcol8]);
        }
#pragma unroll
        for (int n = 0; n < 4; ++n) {
            const bf16x8 ah = *reinterpret_cast<const bf16x8*>(&Ahi[wk * 64 + n * 16 + frow][fcol8]);
            const bf16x8 al = *reinterpret_cast<const bf16x8*>(&Alo[wk * 64 + n * 16 + frow][fcol8]);
#pragma unroll
            for (int m = 0; m < 4; ++m) {
                acc[m][n] = __builtin_amdgcn_mfma_f32_16x16x32_bf16(sh[m], ah, acc[m][n], 0, 0, 0);
                acc[m][n] = __builtin_amdgcn_mfma_f32_16x16x32_bf16(sh[m], al, acc[m][n], 0, 0, 0);
                acc[m][n] = __builtin_amdgcn_mfma_f32_16x16x32_bf16(sl[m], ah, acc[m][n], 0, 0, 0);
            }
        }
        __syncthreads();
    }

#pragma unroll
    for (int m = 0; m < 4; ++m) {
#pragma unroll
        for (int r = 0; r < 4; ++r) {
            const int j = j0 + wj * 64 + m * 16 + (lane >> 4) * 4 + r;
            const float bj = bvec[j];
            unsigned int sum = 0;
#pragma unroll
            for (int n = 0; n < 4; ++n) {
                const int k = k0 + wk * 64 + n * 16 + (lane & 15);
                const float x = acc[m][n][r] + bj;
                if (__builtin_fabsf(x) <= MARGIN) {
                    unsigned int slot = atomicAdd(defer_cnt, 1u);
                    if (slot < defer_cap)
                        defer_list[slot] = ((unsigned int)j << 12) | (unsigned int)k;
                } else if (x > 0.0f) {
                    sum += (unsigned int)hash_coeffs[k];
                }
            }
            sum += (unsigned int)__shfl_xor((int)sum, 1);
            sum += (unsigned int)__shfl_xor((int)sum, 2);
            sum += (unsigned int)__shfl_xor((int)sum, 4);
            sum += (unsigned int)__shfl_xor((int)sum, 8);
            if ((lane & 15) == 0) atomicAdd(&hash_acc[j], sum);
        }
    }
}

// Exact fp64 recompute of deferred dots; one wave per deferred (j,k) pair.
__global__ __launch_bounds__(256)
void opiq_fixup(const float* __restrict__ states,
                const float* __restrict__ actions,
                const float* __restrict__ A,
                const float* __restrict__ bvec,
                const int* __restrict__ hash_coeffs,
                unsigned int* __restrict__ hash_acc,
                const unsigned int* __restrict__ defer_cnt,
                const unsigned int* __restrict__ defer_list,
                unsigned int defer_cap)
{
    const int gtid = blockIdx.x * 256 + threadIdx.x;
    const int wave = gtid >> 6;
    const int lane = gtid & 63;
    const int n_waves = gridDim.x * 4;

    unsigned int n = *defer_cnt;
    if (n > defer_cap) n = defer_cap;

    for (unsigned int e = wave; e < n; e += n_waves) {
        const unsigned int ent = defer_list[e];
        const int j = (int)(ent >> 12);
        const int k = (int)(ent & 4095);
        double part = 0.0;
        const int dbase = lane * 32;
#pragma unroll 8
        for (int t = 0; t < 32; ++t) {
            const int d = dbase + t;
            const float sv = (d == D_SZ) ? actions[j]
                                         : states[(size_t)j * D_SZ + d];
            part = fma((double)sv, (double)A[(size_t)k * KD + d], part);
        }
#pragma unroll
        for (int m = 1; m < 64; m <<= 1)
            part += __shfl_xor(part, m);
        const double x = part + (double)bvec[j];
        if (lane == 0 && x > 0.0)
            atomicAdd(&hash_acc[j], (unsigned int)hash_coeffs[k]);
    }
}

__global__ void opiq_final(const unsigned int* __restrict__ hash_acc,
                           const int* __restrict__ count_table,
                           float* __restrict__ out)
{
    int j = blockIdx.x * 256 + threadIdx.x;
    if (j < B_SZ) {
        unsigned int idx = hash_acc[j] & TABLE_MASK;
        float c = (float)count_table[idx];
        float t = c + 1.0f;
        out[j] = 1.0f / (t * t);
    }
}

extern "C" void kernel_launch(void* const* d_in, const int* in_sizes, int n_in,
                              void* d_out, int out_size, void* d_ws, size_t ws_size,
                              hipStream_t stream) {
    const float* states      = (const float*)d_in[0];
    const float* actions     = (const float*)d_in[1];
    const float* A           = (const float*)d_in[2];
    const float* bvec        = (const float*)d_in[3];
    const int*   count_table = (const int*)d_in[4];
    const int*   hash_coeffs = (const int*)d_in[5];
    float* out = (float*)d_out;

    // ws layout (fast path):
    // [0, 8K)        hash_acc (2048 u32)
    // [8K, 8K+4)     defer_cnt
    // [16K, 16K+4M)  defer_list (1M entries)
    // [16K+4M, ...)  bf16 planes: Shi(8M) Slo(8M) Ahi(16M) Alo(16M)
    const size_t DEFER_OFF  = 16384;
    const size_t DEFER_CAP  = 1u << 20;
    const size_t PLANES_OFF = DEFER_OFF + DEFER_CAP * 4;           // 4.21 MB
    const size_t S_ELEMS = (size_t)B_SZ * KD;                      // 4.19M
    const size_t A_ELEMS = (size_t)K_SZ * KD;                      // 8.39M
    const size_t REQ = PLANES_OFF + 2 * (S_ELEMS + A_ELEMS) * sizeof(ushort_t);

    unsigned int* hash_acc  = (unsigned int*)d_ws;
    unsigned int* defer_cnt = hash_acc + B_SZ;

    if (ws_size >= REQ) {
        unsigned int* defer_list = (unsigned int*)((char*)d_ws + DEFER_OFF);
        ushort_t* Shi = (ushort_t*)((char*)d_ws + PLANES_OFF);
        ushort_t* Slo = Shi + S_ELEMS;
        ushort_t* Ahi = Slo + S_ELEMS;
        ushort_t* Alo = Ahi + A_ELEMS;

        hipMemsetAsync(d_ws, 0, DEFER_OFF, stream);
        opiq_split<<<4096, 256, 0, stream>>>(states, actions, A, Shi, Slo, Ahi, Alo);
        opiq_gemm_mfma<<<512, 256, 0, stream>>>(Shi, Slo, Ahi, Alo, bvec,
                                                hash_coeffs, hash_acc,
                                                defer_cnt, defer_list,
                                                (unsigned int)DEFER_CAP);
        opiq_fixup<<<128, 256, 0, stream>>>(states, actions, A, bvec, hash_coeffs,
                                            hash_acc, defer_cnt, defer_list,
                                            (unsigned int)DEFER_CAP);
    } else {
        // fallback: R2 path, defer list right after counter
        unsigned int* defer_list = hash_acc + B_SZ + 1;
        unsigned int  defer_cap  = 0;
        if (ws_size > (B_SZ + 1) * sizeof(unsigned int))
            defer_cap = (unsigned int)((ws_size - (B_SZ + 1) * sizeof(unsigned int))
                                       / sizeof(unsigned int));
        if (defer_cap > (1u << 20)) defer_cap = 1u << 20;

        hipMemsetAsync(d_ws, 0, (B_SZ + 1) * sizeof(unsigned int), stream);
        dim3 grid(K_SZ / TK, B_SZ / TJ);
        opiq_gemm_hash<<<grid, 256, 0, stream>>>(states, actions, A, bvec,
                                                 hash_coeffs, hash_acc,
                                                 defer_cnt, defer_list, defer_cap);
        opiq_fixup<<<128, 256, 0, stream>>>(states, actions, A, bvec, hash_coeffs,
                                            hash_acc, defer_cnt, defer_list, defer_cap);
    }
    opiq_final<<<(B_SZ + 255) / 256, 256, 0, stream>>>(hash_acc, count_table, out);
}